// Round 12
// baseline (478.552 us; speedup 1.0000x reference)
//
#include <hip/hip_runtime.h>
#include <hip/hip_fp16.h>
#include <cmath>

static constexpr int NN = 100000;   // nodes
static constexpr int NE = 1600000;  // edges
static const size_t NW = (size_t)NN * 32;
static constexpr int NSLICE = 8;
static constexpr int SLICE_W = 12500;   // NN / NSLICE
static constexpr int SBCAP = 28000;     // per-(slice,xcd-group) sub-bucket cap
                                        // expected 25000, sigma ~157 -> 19 sigma
static constexpr int MCAP = 4096;       // masked-node list capacity
static constexpr int FB_BPG = 128;      // fillB blocks per slice group

// csr entry: bits[16:0]=src (<131072), bits[30:17]=fp16 bit-pattern of ew.
__device__ __forceinline__ float ent_w(unsigned e)
{
    return __half2float(__ushort_as_half((unsigned short)(e >> 17)));
}
__device__ __forceinline__ int ent_s(unsigned e)
{
    int s = (int)(e & 0x1FFFF);
    return s < NN ? s : NN - 1;   // hardened: OOB -> wrong value, not fault
}

__device__ __forceinline__ float4 pack8(const float* v)
{
    union { __half2 h2[4]; float4 f4; } u;
    u.h2[0] = __floats2half2_rn(v[0], v[1]);
    u.h2[1] = __floats2half2_rn(v[2], v[3]);
    u.h2[2] = __floats2half2_rn(v[4], v[5]);
    u.h2[3] = __floats2half2_rn(v[6], v[7]);
    return u.f4;
}

// ---------------------------------------------------------------------------
// Pass A v2: one edge per thread. Degree histogram + mask collection +
// ballot-aggregated bucketing into 64 sub-buckets (slice x xcd-group).
// No per-element LDS atomics (R11's serialization bug): per-wave counts via
// __ballot, 32-int LDS combine, 8 global atomics per block, coalesced writes.
// ---------------------------------------------------------------------------
__global__ void __launch_bounds__(256) bucket_k(
    const int* __restrict__ src, const int* __restrict__ dst,
    const float* __restrict__ ew, const int* __restrict__ curp,
    int* __restrict__ deg, int* __restrict__ maskb, int* __restrict__ mcount,
    int* __restrict__ mlist, int* __restrict__ bcur, uint2* __restrict__ buckets)
{
    __shared__ int sCnt[4][8];      // per-wave bucket counts
    __shared__ int sWaveBase[4][8];
    __shared__ int sBlockBase[8];
    int t = threadIdx.x;
    int w = t >> 6;
    int lane = t & 63;
    int xg = blockIdx.x & 7;        // xcd-group heuristic (blockIdx round-robin)
    int e = blockIdx.x * 256 + t;   // NE % 256 == 0 -> always < NE
    int d = dst[e];
    bool valid = ((unsigned)d < (unsigned)NN);
    int s = src[e];
    int b = valid ? (d / SLICE_W) : 0;
    if (b > 7) b = 7;
    if (valid) {
        atomicAdd(deg + d, 1);
        if (s == curp[0]) {
            if (atomicExch(maskb + d, 1) == 0) {
                int idx = atomicAdd(mcount, 1);
                if (idx < MCAP) mlist[idx] = d;
            }
        }
    }
    unsigned bits = __half_as_ushort(__float2half(ew[e]));
    uint2 ent;
    ent.x = ((unsigned)s & 0x1FFFF) | (bits << 17);
    ent.y = (unsigned)d;
    unsigned long long ltmask = (1ull << lane) - 1ull;
    int pre = 0;
#pragma unroll
    for (int bb = 0; bb < 8; ++bb) {
        unsigned long long m = __ballot(valid && (b == bb));
        if (lane == 0) sCnt[w][bb] = (int)__popcll(m);
        if (valid && b == bb) pre = (int)__popcll(m & ltmask);
    }
    __syncthreads();
    if (t < 8) {
        int bb = t;
        int c0 = sCnt[0][bb], c1 = sCnt[1][bb], c2 = sCnt[2][bb], c3 = sCnt[3][bb];
        sWaveBase[0][bb] = 0;
        sWaveBase[1][bb] = c0;
        sWaveBase[2][bb] = c0 + c1;
        sWaveBase[3][bb] = c0 + c1 + c2;
        int tot = c0 + c1 + c2 + c3;
        int base = tot ? atomicAdd(bcur + ((bb << 3) | xg), tot) : 0;
        sBlockBase[bb] = base;
    }
    __syncthreads();
    if (valid) {
        unsigned pos = (unsigned)(sBlockBase[b] + sWaveBase[w][b] + pre);
        if (pos < (unsigned)SBCAP)
            buckets[(size_t)((b << 3) | xg) * SBCAP + pos] = ent;
    }
}

__global__ void __launch_bounds__(256) block_sum_k(const int* __restrict__ deg,
                                                   int* __restrict__ bsum)
{
    int n = blockIdx.x * 256 + threadIdx.x;
    int d = (n < NN) ? deg[n] : 0;
#pragma unroll
    for (int k = 32; k; k >>= 1) d += __shfl_xor(d, k, 64);
    __shared__ int s[4];
    if ((threadIdx.x & 63) == 0) s[threadIdx.x >> 6] = d;
    __syncthreads();
    if (threadIdx.x == 0) bsum[blockIdx.x] = s[0] + s[1] + s[2] + s[3];
}

__global__ void __launch_bounds__(512) scan_bsum_k(const int* __restrict__ bsum,
                                                   int np, int* __restrict__ ebase)
{
    __shared__ int tmp[512];
    int t = threadIdx.x;
    int v = (t < np) ? bsum[t] : 0;
    tmp[t] = v;
    __syncthreads();
    for (int s = 1; s < 512; s <<= 1) {
        int x = tmp[t];
        int add = (t >= s) ? tmp[t - s] : 0;
        __syncthreads();
        tmp[t] = x + add;
        __syncthreads();
    }
    if (t < np) ebase[t] = tmp[t] - v;
}

__global__ void __launch_bounds__(256) scan_write_k(const int* __restrict__ deg,
                                                    const int* __restrict__ ebase,
                                                    int* __restrict__ off,
                                                    int* __restrict__ cursor)
{
    __shared__ int tmp[256];
    int t = threadIdx.x;
    int n = blockIdx.x * 256 + t;
    int d = (n < NN) ? deg[n] : 0;
    tmp[t] = d;
    __syncthreads();
    for (int s = 1; s < 256; s <<= 1) {
        int x = tmp[t];
        int add = (t >= s) ? tmp[t - s] : 0;
        __syncthreads();
        tmp[t] = x + add;
        __syncthreads();
    }
    int excl = tmp[t] - d;
    if (n < NN) {
        int base = ebase[blockIdx.x] + excl;
        off[n] = base;
        cursor[n] = base;
    }
}

// ---------------------------------------------------------------------------
// Pass B: per-slice CSR fill. Group g (blockIdx%8 ~ one XCD) streams its
// slice's 8 sub-buckets (~1.76 MB total) and scatters into its 800 KB csr
// slice + 50 KB cursors — working set fits one XCD L2.
// ---------------------------------------------------------------------------
__global__ void __launch_bounds__(256) fillB_k(const uint2* __restrict__ buckets,
                                               const int* __restrict__ bcur,
                                               int* __restrict__ cursor,
                                               unsigned* __restrict__ csr4)
{
    int g = blockIdx.x & (NSLICE - 1);
    int b = blockIdx.x >> 3;
    for (int xg = 0; xg < 8; ++xg) {
        int cnt = bcur[(g << 3) | xg];
        if (cnt > SBCAP) cnt = SBCAP;
        const uint2* bk = buckets + (size_t)((g << 3) | xg) * SBCAP;
        for (int i = b * 256 + (int)threadIdx.x; i < cnt; i += FB_BPG * 256) {
            uint2 e = bk[i];
            unsigned d = e.y;
            if (d >= (unsigned)NN) continue;
            unsigned pos = (unsigned)atomicAdd(cursor + d, 1);
            if (pos < (unsigned)NE) csr4[pos] = e.x;
        }
    }
}

// ---------------------------------------------------------------------------
// mm1: proj1 = fp16(x@Win_rel), root1 = fp16(x@Win_root + bin).
// Register-blocked 4 nodes x 8 cols per thread; 128 nodes/block.
// ---------------------------------------------------------------------------
__global__ void __launch_bounds__(256) mm1_k(
    const float* __restrict__ x, const float* __restrict__ Wrel,
    const float* __restrict__ Wroot, const float* __restrict__ bin,
    __half* __restrict__ proj1, __half* __restrict__ root1)
{
    __shared__ float sX[128 * 65];
    __shared__ float sW[64 * 68];
    int t = threadIdx.x;
    for (int i = t; i < 64 * 32; i += 256) {
        int k = i >> 5, j = i & 31;
        sW[k * 68 + j] = Wrel[i];
        sW[k * 68 + 32 + j] = Wroot[i];
    }
    int base = blockIdx.x * 128;
    for (int i = t; i < 2048; i += 256) {
        int node = i >> 4;
        int k = (i & 15) * 4;
        int n = base + node;
        if (n >= NN) n = NN - 1;
        float4 v = *(const float4*)(x + (size_t)n * 64 + k);
        float* p = sX + node * 65 + k;
        p[0] = v.x; p[1] = v.y; p[2] = v.z; p[3] = v.w;
    }
    __syncthreads();
    int cg = t & 7;
    int ng = t >> 3;
    int c0 = 8 * cg;
    float acc[4][8] = {};
    for (int k = 0; k < 64; ++k) {
        float xv0 = sX[(4 * ng + 0) * 65 + k];
        float xv1 = sX[(4 * ng + 1) * 65 + k];
        float xv2 = sX[(4 * ng + 2) * 65 + k];
        float xv3 = sX[(4 * ng + 3) * 65 + k];
        float4 w0 = *(const float4*)(sW + k * 68 + c0);
        float4 w1 = *(const float4*)(sW + k * 68 + c0 + 4);
        const float* wp = (const float*)&w0;
#pragma unroll
        for (int j = 0; j < 4; ++j) {
            float w = wp[j];
            acc[0][j] = fmaf(xv0, w, acc[0][j]);
            acc[1][j] = fmaf(xv1, w, acc[1][j]);
            acc[2][j] = fmaf(xv2, w, acc[2][j]);
            acc[3][j] = fmaf(xv3, w, acc[3][j]);
        }
        const float* wq = (const float*)&w1;
#pragma unroll
        for (int j = 0; j < 4; ++j) {
            float w = wq[j];
            acc[0][4 + j] = fmaf(xv0, w, acc[0][4 + j]);
            acc[1][4 + j] = fmaf(xv1, w, acc[1][4 + j]);
            acc[2][4 + j] = fmaf(xv2, w, acc[2][4 + j]);
            acc[3][4 + j] = fmaf(xv3, w, acc[3][4 + j]);
        }
    }
#pragma unroll
    for (int r = 0; r < 4; ++r) {
        int n = base + 4 * ng + r;
        if (n >= NN) break;
        if (cg < 4) {
            *(float4*)(proj1 + (size_t)n * 32 + c0) = pack8(acc[r]);
        } else {
            int c = c0 - 32;
            float v[8];
#pragma unroll
            for (int j = 0; j < 8; ++j) v[j] = acc[r][j] + bin[c + j];
            *(float4*)(root1 + (size_t)n * 32 + c) = pack8(v);
        }
    }
}

// ---------------------------------------------------------------------------
// mm2: proj2 = fp16(h1@Wh_rel), root2 = fp16(h1@Wh_root + bh). K=32.
// ---------------------------------------------------------------------------
__global__ void __launch_bounds__(256) mm2_k(
    const __half* __restrict__ h1, const float* __restrict__ Wrel,
    const float* __restrict__ Wroot, const float* __restrict__ bh,
    __half* __restrict__ proj2, __half* __restrict__ root2)
{
    __shared__ float sX[128 * 33];
    __shared__ float sW[32 * 68];
    int t = threadIdx.x;
    for (int i = t; i < 32 * 32; i += 256) {
        int k = i >> 5, j = i & 31;
        sW[k * 68 + j] = Wrel[i];
        sW[k * 68 + 32 + j] = Wroot[i];
    }
    int base = blockIdx.x * 128;
    for (int i = t; i < 512; i += 256) {
        int node = i >> 2;
        int hs = (i & 3) * 8;
        int n = base + node;
        if (n >= NN) n = NN - 1;
        float4 v = *(const float4*)(h1 + (size_t)n * 32 + hs);
        const __half2* hp = (const __half2*)&v;
        float* p = sX + node * 33 + hs;
#pragma unroll
        for (int u = 0; u < 4; ++u) {
            float2 f2 = __half22float2(hp[u]);
            p[2 * u] = f2.x;
            p[2 * u + 1] = f2.y;
        }
    }
    __syncthreads();
    int cg = t & 7;
    int ng = t >> 3;
    int c0 = 8 * cg;
    float acc[4][8] = {};
    for (int k = 0; k < 32; ++k) {
        float xv0 = sX[(4 * ng + 0) * 33 + k];
        float xv1 = sX[(4 * ng + 1) * 33 + k];
        float xv2 = sX[(4 * ng + 2) * 33 + k];
        float xv3 = sX[(4 * ng + 3) * 33 + k];
        float4 w0 = *(const float4*)(sW + k * 68 + c0);
        float4 w1 = *(const float4*)(sW + k * 68 + c0 + 4);
        const float* wp = (const float*)&w0;
#pragma unroll
        for (int j = 0; j < 4; ++j) {
            float w = wp[j];
            acc[0][j] = fmaf(xv0, w, acc[0][j]);
            acc[1][j] = fmaf(xv1, w, acc[1][j]);
            acc[2][j] = fmaf(xv2, w, acc[2][j]);
            acc[3][j] = fmaf(xv3, w, acc[3][j]);
        }
        const float* wq = (const float*)&w1;
#pragma unroll
        for (int j = 0; j < 4; ++j) {
            float w = wq[j];
            acc[0][4 + j] = fmaf(xv0, w, acc[0][4 + j]);
            acc[1][4 + j] = fmaf(xv1, w, acc[1][4 + j]);
            acc[2][4 + j] = fmaf(xv2, w, acc[2][4 + j]);
            acc[3][4 + j] = fmaf(xv3, w, acc[3][4 + j]);
        }
    }
#pragma unroll
    for (int r = 0; r < 4; ++r) {
        int n = base + 4 * ng + r;
        if (n >= NN) break;
        if (cg < 4) {
            *(float4*)(proj2 + (size_t)n * 32 + c0) = pack8(acc[r]);
        } else {
            int c = c0 - 32;
            float v[8];
#pragma unroll
            for (int j = 0; j < 8; ++j) v[j] = acc[r][j] + bh[c + j];
            *(float4*)(root2 + (size_t)n * 32 + c) = pack8(v);
        }
    }
}

// ---------------------------------------------------------------------------
// agg1 v4: 4 lanes per node (q = feature octet), 16 nodes/wave.
// ---------------------------------------------------------------------------
__global__ void __launch_bounds__(256) agg1_v4(
    const __half* __restrict__ proj1, const __half* __restrict__ root1,
    const unsigned* __restrict__ csr4, const int* __restrict__ off,
    const int* __restrict__ deg, __half* __restrict__ h1)
{
    int t = threadIdx.x;
    int q = t & 3;
    int f0 = q * 8;
    int n = blockIdx.x * 64 + (t >> 2);
    if (n >= NN) return;
    int st = off[n];
    int dg = deg[n];
    if (st < 0) st = 0;
    if (st > NE) st = NE;
    if (dg < 0) dg = 0;
    if (dg > NE - st) dg = NE - st;
    float acc[8] = {0.f, 0.f, 0.f, 0.f, 0.f, 0.f, 0.f, 0.f};
    int i = 0;
    for (; i + 1 < dg; i += 2) {
        unsigned e0 = csr4[st + i];
        unsigned e1 = csr4[st + i + 1];
        float w0 = ent_w(e0), w1 = ent_w(e1);
        float4 r0 = *(const float4*)(proj1 + (size_t)ent_s(e0) * 32 + f0);
        float4 r1 = *(const float4*)(proj1 + (size_t)ent_s(e1) * 32 + f0);
        const __half2* h0 = (const __half2*)&r0;
        const __half2* h1p = (const __half2*)&r1;
#pragma unroll
        for (int u = 0; u < 4; ++u) {
            float2 a = __half22float2(h0[u]);
            float2 b = __half22float2(h1p[u]);
            acc[2 * u] = fmaf(w0, a.x, acc[2 * u]);
            acc[2 * u + 1] = fmaf(w0, a.y, acc[2 * u + 1]);
            acc[2 * u] = fmaf(w1, b.x, acc[2 * u]);
            acc[2 * u + 1] = fmaf(w1, b.y, acc[2 * u + 1]);
        }
    }
    if (i < dg) {
        unsigned e0 = csr4[st + i];
        float w0 = ent_w(e0);
        float4 r0 = *(const float4*)(proj1 + (size_t)ent_s(e0) * 32 + f0);
        const __half2* h0 = (const __half2*)&r0;
#pragma unroll
        for (int u = 0; u < 4; ++u) {
            float2 a = __half22float2(h0[u]);
            acc[2 * u] = fmaf(w0, a.x, acc[2 * u]);
            acc[2 * u + 1] = fmaf(w0, a.y, acc[2 * u + 1]);
        }
    }
    float4 rr = *(const float4*)(root1 + (size_t)n * 32 + f0);
    const __half2* rp = (const __half2*)&rr;
    float h[8];
#pragma unroll
    for (int u = 0; u < 4; ++u) {
        float2 f2 = __half22float2(rp[u]);
        h[2 * u] = fmaxf(acc[2 * u] + f2.x, 0.f);
        h[2 * u + 1] = fmaxf(acc[2 * u + 1] + f2.y, 0.f);
    }
    *(float4*)(h1 + (size_t)n * 32 + f0) = pack8(h);
}

// ---------------------------------------------------------------------------
// agg2 v4: same gather structure; epilogue computes the 4 OUT=1 head dots.
// ---------------------------------------------------------------------------
__global__ void __launch_bounds__(256) agg2_v4(
    const __half* __restrict__ proj2, const __half* __restrict__ root2,
    const float* __restrict__ Wp_rel, const float* __restrict__ Wp_root,
    const float* __restrict__ bp, const float* __restrict__ Wv_rel,
    const float* __restrict__ Wv_root, const float* __restrict__ bv,
    const unsigned* __restrict__ csr4, const int* __restrict__ off,
    const int* __restrict__ deg, float2* __restrict__ pv,
    float* __restrict__ pbase, float* __restrict__ vbase)
{
    __shared__ float sHead[4 * 32];
    if (threadIdx.x < 32) {
        sHead[threadIdx.x] = Wp_rel[threadIdx.x];
        sHead[32 + threadIdx.x] = Wp_root[threadIdx.x];
        sHead[64 + threadIdx.x] = Wv_rel[threadIdx.x];
        sHead[96 + threadIdx.x] = Wv_root[threadIdx.x];
    }
    __syncthreads();
    int t = threadIdx.x;
    int q = t & 3;
    int f0 = q * 8;
    int n = blockIdx.x * 64 + (t >> 2);
    if (n >= NN) return;
    int st = off[n];
    int dg = deg[n];
    if (st < 0) st = 0;
    if (st > NE) st = NE;
    if (dg < 0) dg = 0;
    if (dg > NE - st) dg = NE - st;
    float acc[8] = {0.f, 0.f, 0.f, 0.f, 0.f, 0.f, 0.f, 0.f};
    int i = 0;
    for (; i + 1 < dg; i += 2) {
        unsigned e0 = csr4[st + i];
        unsigned e1 = csr4[st + i + 1];
        float w0 = ent_w(e0), w1 = ent_w(e1);
        float4 r0 = *(const float4*)(proj2 + (size_t)ent_s(e0) * 32 + f0);
        float4 r1 = *(const float4*)(proj2 + (size_t)ent_s(e1) * 32 + f0);
        const __half2* h0 = (const __half2*)&r0;
        const __half2* h1p = (const __half2*)&r1;
#pragma unroll
        for (int u = 0; u < 4; ++u) {
            float2 a = __half22float2(h0[u]);
            float2 b = __half22float2(h1p[u]);
            acc[2 * u] = fmaf(w0, a.x, acc[2 * u]);
            acc[2 * u + 1] = fmaf(w0, a.y, acc[2 * u + 1]);
            acc[2 * u] = fmaf(w1, b.x, acc[2 * u]);
            acc[2 * u + 1] = fmaf(w1, b.y, acc[2 * u + 1]);
        }
    }
    if (i < dg) {
        unsigned e0 = csr4[st + i];
        float w0 = ent_w(e0);
        float4 r0 = *(const float4*)(proj2 + (size_t)ent_s(e0) * 32 + f0);
        const __half2* h0 = (const __half2*)&r0;
#pragma unroll
        for (int u = 0; u < 4; ++u) {
            float2 a = __half22float2(h0[u]);
            acc[2 * u] = fmaf(w0, a.x, acc[2 * u]);
            acc[2 * u + 1] = fmaf(w0, a.y, acc[2 * u + 1]);
        }
    }
    float4 rr = *(const float4*)(root2 + (size_t)n * 32 + f0);
    const __half2* rp = (const __half2*)&rr;
    float h[8];
#pragma unroll
    for (int u = 0; u < 4; ++u) {
        float2 f2 = __half22float2(rp[u]);
        h[2 * u] = fmaxf(acc[2 * u] + f2.x, 0.f);
        h[2 * u + 1] = fmaxf(acc[2 * u + 1] + f2.y, 0.f);
    }
    float prv = 0.f, pov = 0.f, vrv = 0.f, vov = 0.f;
#pragma unroll
    for (int j = 0; j < 8; ++j) {
        prv = fmaf(h[j], sHead[f0 + j], prv);
        pov = fmaf(h[j], sHead[32 + f0 + j], pov);
        vrv = fmaf(h[j], sHead[64 + f0 + j], vrv);
        vov = fmaf(h[j], sHead[96 + f0 + j], vov);
    }
#pragma unroll
    for (int m = 1; m <= 2; m <<= 1) {
        prv += __shfl_xor(prv, m, 64);
        pov += __shfl_xor(pov, m, 64);
        vrv += __shfl_xor(vrv, m, 64);
        vov += __shfl_xor(vov, m, 64);
    }
    if (q == 0) {
        pv[n] = make_float2(prv, vrv);
        pbase[n] = pov + bp[0];
        vbase[n] = vov + bv[0];
    }
}

// ---------------------------------------------------------------------------
// Single-block masked softmax over the ~64 reachable nodes; sparse writes.
// ---------------------------------------------------------------------------
__global__ void __launch_bounds__(256) masked_softmax_k(
    const int* __restrict__ mlist, const int* __restrict__ mcount,
    const unsigned* __restrict__ csr4, const int* __restrict__ off,
    const int* __restrict__ deg, const float2* __restrict__ pv,
    const float* __restrict__ pbase, const float* __restrict__ vbase,
    float* __restrict__ out_p, float* __restrict__ out_v)
{
    __shared__ float sPm[MCAP];
    __shared__ float sV[MCAP];
    __shared__ int sN[MCAP];
    __shared__ float sMx, sSum;
    __shared__ float sred[4];
    int m = mcount[0];
    if (m > MCAP) m = MCAP;
    if (m < 0) m = 0;
    for (int idx = threadIdx.x; idx < m; idx += 256) {
        int n = mlist[idx];
        if ((unsigned)n >= (unsigned)NN) n = 0;
        sN[idx] = n;
        int st = off[n];
        int dg = deg[n];
        if (st < 0) st = 0;
        if (st > NE) st = NE;
        if (dg < 0) dg = 0;
        if (dg > NE - st) dg = NE - st;
        float pa = 0.f, va = 0.f;
        for (int i = 0; i < dg; ++i) {
            unsigned ent = csr4[st + i];
            int s = ent_s(ent);
            float w = ent_w(ent);
            float2 tv = pv[s];
            pa = fmaf(tv.x, w, pa);
            va = fmaf(tv.y, w, va);
        }
        float p = pa + pbase[n];
        sPm[idx] = (p == 0.f) ? -INFINITY : p;
        sV[idx] = va + vbase[n];
    }
    __syncthreads();
    float mx = -INFINITY;
    for (int i = threadIdx.x; i < m; i += 256) mx = fmaxf(mx, sPm[i]);
#pragma unroll
    for (int k = 32; k; k >>= 1) mx = fmaxf(mx, __shfl_xor(mx, k, 64));
    if ((threadIdx.x & 63) == 0) sred[threadIdx.x >> 6] = mx;
    __syncthreads();
    if (threadIdx.x == 0)
        sMx = fmaxf(fmaxf(sred[0], sred[1]), fmaxf(sred[2], sred[3]));
    __syncthreads();
    float sum = 0.f;
    for (int i = threadIdx.x; i < m; i += 256) {
        float x = sPm[i];
        sum += (x == -INFINITY) ? 0.f : expf(x - sMx);
    }
#pragma unroll
    for (int k = 32; k; k >>= 1) sum += __shfl_xor(sum, k, 64);
    if ((threadIdx.x & 63) == 0) sred[threadIdx.x >> 6] = sum;
    __syncthreads();
    if (threadIdx.x == 0) sSum = sred[0] + sred[1] + sred[2] + sred[3];
    __syncthreads();
    for (int idx = threadIdx.x; idx < m; idx += 256) {
        int n = sN[idx];
        float x = sPm[idx];
        out_p[n] = (x == -INFINITY) ? 0.f : expf(x - sMx) / sSum;
        out_v[n] = sV[idx];
    }
}

// ---------------------------------------------------------------------------
extern "C" void kernel_launch(void* const* d_in, const int* in_sizes, int n_in,
                              void* d_out, int out_size, void* d_ws,
                              size_t ws_size, hipStream_t stream)
{
    const float* x        = (const float*)d_in[0];
    const int*   ei       = (const int*)d_in[1];
    const float* ew       = (const float*)d_in[2];
    const int*   cur      = (const int*)d_in[3];
    const float* Win_rel  = (const float*)d_in[4];
    const float* bin_rel  = (const float*)d_in[5];
    const float* Win_root = (const float*)d_in[6];
    const float* Wh_rel   = (const float*)d_in[7];
    const float* bh_rel   = (const float*)d_in[8];
    const float* Wh_root  = (const float*)d_in[9];
    const float* Wp_rel   = (const float*)d_in[10];
    const float* bp       = (const float*)d_in[11];
    const float* Wp_root  = (const float*)d_in[12];
    const float* Wv_rel   = (const float*)d_in[13];
    const float* bv       = (const float*)d_in[14];
    const float* Wv_root  = (const float*)d_in[15];

    const int* srcA = ei;
    const int* dstA = ei + NE;

    // Workspace layout (~43 MB). Buckets (64*28000*8 = 14.3 MB) overlay
    // proj1/root1/h1 (19.2 MB) — buckets dead before mm1 writes proj1.
    char* w8 = (char*)d_ws;
    unsigned* csr4 = (unsigned*)w8;          // 6.4 MB
    int* deg    = (int*)(csr4 + NE);         // NN  } zeroed
    int* maskb  = deg + NN;                  // NN  }  together
    int* mcount = maskb + NN;                // 8   }
    int* off    = mcount + 8;
    int* cursor = off + NN;
    int* bsum   = cursor + NN;               // 512
    int* ebase  = bsum + 512;                // 512
    int* mlist  = ebase + 512;               // MCAP
    int* bcur   = mlist + MCAP;              // 64  } zeroed separately
    __half* proj1 = (__half*)(bcur + 64);    // U region start (19.2 MB)
    __half* root1 = proj1 + NW;
    __half* h1    = root1 + NW;
    uint2* buckets = (uint2*)proj1;          // overlays U (14.3 MB < 19.2 MB)
    __half* proj2 = h1 + NW;                 // 6.4 MB
    __half* root2 = proj2 + NW;              // 6.4 MB
    float2* pv    = (float2*)(root2 + NW);   // 800 KB
    float* pbase  = (float*)(pv + NN);       // 400 KB
    float* vbase  = pbase + NN;              // 400 KB

    float* out_p = (float*)d_out;
    float* out_v = out_p + NN;

    const int NB_N   = (NN + 255) / 256;    // 391
    const int NB_BKA = NE / 256;            // 6250 (exact)
    const int NB_MM  = (NN + 127) / 128;    // 782
    const int NB_AGG = (NN + 63) / 64;      // 1563

    hipMemsetAsync(deg, 0, (2 * (size_t)NN + 8) * sizeof(int), stream);
    hipMemsetAsync(bcur, 0, 64 * sizeof(int), stream);
    hipMemsetAsync(d_out, 0, 2 * (size_t)NN * sizeof(float), stream);

    // --- CSR build: ballot-aggregated bucket pass, scans, L2-local fill ---
    bucket_k<<<NB_BKA, 256, 0, stream>>>(srcA, dstA, ew, cur, deg, maskb,
                                         mcount, mlist, bcur, buckets);
    block_sum_k<<<NB_N, 256, 0, stream>>>(deg, bsum);
    scan_bsum_k<<<1, 512, 0, stream>>>(bsum, NB_N, ebase);
    scan_write_k<<<NB_N, 256, 0, stream>>>(deg, ebase, off, cursor);
    fillB_k<<<NSLICE * FB_BPG, 256, 0, stream>>>(buckets, bcur, cursor, csr4);

    // --- layer chain ---
    mm1_k<<<NB_MM, 256, 0, stream>>>(x, Win_rel, Win_root, bin_rel, proj1,
                                     root1);
    agg1_v4<<<NB_AGG, 256, 0, stream>>>(proj1, root1, csr4, off, deg, h1);
    mm2_k<<<NB_MM, 256, 0, stream>>>(h1, Wh_rel, Wh_root, bh_rel, proj2, root2);
    agg2_v4<<<NB_AGG, 256, 0, stream>>>(proj2, root2, Wp_rel, Wp_root, bp,
                                        Wv_rel, Wv_root, bv, csr4, off, deg,
                                        pv, pbase, vbase);
    // --- masked softmax (sparse outputs) ---
    masked_softmax_k<<<1, 256, 0, stream>>>(mlist, mcount, csr4, off, deg, pv,
                                            pbase, vbase, out_p, out_v);
}

// Round 13
// 370.378 us; speedup vs baseline: 1.2921x; 1.2921x over previous
//
#include <hip/hip_runtime.h>
#include <hip/hip_fp16.h>
#include <cmath>

static constexpr int NN = 100000;   // nodes
static constexpr int NE = 1600000;  // edges
static const size_t NW = (size_t)NN * 32;
static constexpr int NSLICE = 8;
static constexpr int SLICE_W = 12500;   // NN / NSLICE
static constexpr int NBK = NE / 256;    // 6250 edge blocks (exact)
static constexpr int BCAP_B = 220000;   // per-slice bucket capacity (exp 200k)
static constexpr int MCAP = 4096;       // masked-node list capacity
static constexpr int FB_BPG = 128;      // fillB blocks per slice group

// csr entry: bits[16:0]=src (<131072), bits[30:17]=fp16 bit-pattern of ew.
__device__ __forceinline__ float ent_w(unsigned e)
{
    return __half2float(__ushort_as_half((unsigned short)(e >> 17)));
}
__device__ __forceinline__ int ent_s(unsigned e)
{
    int s = (int)(e & 0x1FFFF);
    return s < NN ? s : NN - 1;   // hardened: OOB -> wrong value, not fault
}

__device__ __forceinline__ float4 pack8(const float* v)
{
    union { __half2 h2[4]; float4 f4; } u;
    u.h2[0] = __floats2half2_rn(v[0], v[1]);
    u.h2[1] = __floats2half2_rn(v[2], v[3]);
    u.h2[2] = __floats2half2_rn(v[4], v[5]);
    u.h2[3] = __floats2half2_rn(v[6], v[7]);
    return u.f4;
}

// ---------------------------------------------------------------------------
// Pass A1: ballot-count per-(block, slice) + deg histogram + mask collection.
// NO reservation atomics (R12's bug: block stores stalled on contended
// same-line global atomics). Counts go to blkcnt[8][NBK] for an exact scan.
// ---------------------------------------------------------------------------
__global__ void __launch_bounds__(256) countA_k(
    const int* __restrict__ src, const int* __restrict__ dst,
    const int* __restrict__ curp, int* __restrict__ deg,
    int* __restrict__ maskb, int* __restrict__ mcount, int* __restrict__ mlist,
    int* __restrict__ blkcnt)
{
    __shared__ int sCnt[4][8];
    int t = threadIdx.x, w = t >> 6, lane = t & 63;
    int e = blockIdx.x * 256 + t;      // NE % 256 == 0
    int d = dst[e];
    bool valid = ((unsigned)d < (unsigned)NN);
    int b = valid ? (d / SLICE_W) : 0;
    if (b > 7) b = 7;
    if (valid) {
        atomicAdd(deg + d, 1);
        if (src[e] == curp[0]) {
            if (atomicExch(maskb + d, 1) == 0) {
                int idx = atomicAdd(mcount, 1);
                if (idx < MCAP) mlist[idx] = d;
            }
        }
    }
#pragma unroll
    for (int bb = 0; bb < 8; ++bb) {
        unsigned long long m = __ballot(valid && (b == bb));
        if (lane == 0) sCnt[w][bb] = (int)__popcll(m);
    }
    __syncthreads();
    if (t < 8)
        blkcnt[t * NBK + blockIdx.x] =
            sCnt[0][t] + sCnt[1][t] + sCnt[2][t] + sCnt[3][t];
}

// Exclusive scan of blkcnt[b][*] -> blkbase[b][*]; totals -> btot[b].
// 8 blocks, one per slice-bucket.
__global__ void __launch_bounds__(256) scan_blk_k(
    const int* __restrict__ blkcnt, int* __restrict__ blkbase,
    int* __restrict__ btot)
{
    __shared__ int tmp[256];
    __shared__ int carry;
    int b = blockIdx.x;
    const int* in = blkcnt + b * NBK;
    int* out = blkbase + b * NBK;
    if (threadIdx.x == 0) carry = 0;
    __syncthreads();
    for (int base = 0; base < NBK; base += 256) {
        int i = base + threadIdx.x;
        int v = (i < NBK) ? in[i] : 0;
        tmp[threadIdx.x] = v;
        __syncthreads();
        for (int s = 1; s < 256; s <<= 1) {
            int x = tmp[threadIdx.x];
            int a = (threadIdx.x >= s) ? tmp[threadIdx.x - s] : 0;
            __syncthreads();
            tmp[threadIdx.x] = x + a;
            __syncthreads();
        }
        if (i < NBK) out[i] = carry + tmp[threadIdx.x] - v;
        __syncthreads();
        if (threadIdx.x == 255) carry += tmp[255];
        __syncthreads();
    }
    if (threadIdx.x == 0) btot[b] = carry;
}

// Pass A2: recompute ballots, write entries at deterministic scanned offsets.
// Buckets end up fully contiguous; no store depends on any atomic.
__global__ void __launch_bounds__(256) writeA_k(
    const int* __restrict__ src, const int* __restrict__ dst,
    const float* __restrict__ ew, const int* __restrict__ blkbase,
    uint2* __restrict__ buckets)
{
    __shared__ int sCnt[4][8];
    __shared__ int sWaveBase[4][8];
    __shared__ int sBlockBase[8];
    int t = threadIdx.x, w = t >> 6, lane = t & 63;
    int e = blockIdx.x * 256 + t;
    int d = dst[e];
    bool valid = ((unsigned)d < (unsigned)NN);
    int b = valid ? (d / SLICE_W) : 0;
    if (b > 7) b = 7;
    unsigned bits = __half_as_ushort(__float2half(ew[e]));
    uint2 ent;
    ent.x = ((unsigned)src[e] & 0x1FFFF) | (bits << 17);
    ent.y = (unsigned)d;
    unsigned long long lt = (1ull << lane) - 1ull;
    int pre = 0;
#pragma unroll
    for (int bb = 0; bb < 8; ++bb) {
        unsigned long long m = __ballot(valid && (b == bb));
        if (lane == 0) sCnt[w][bb] = (int)__popcll(m);
        if (valid && b == bb) pre = (int)__popcll(m & lt);
    }
    __syncthreads();
    if (t < 8) {
        int bb = t;
        int c0 = sCnt[0][bb], c1 = sCnt[1][bb], c2 = sCnt[2][bb];
        sWaveBase[0][bb] = 0;
        sWaveBase[1][bb] = c0;
        sWaveBase[2][bb] = c0 + c1;
        sWaveBase[3][bb] = c0 + c1 + c2;
        sBlockBase[bb] = blkbase[bb * NBK + blockIdx.x];
    }
    __syncthreads();
    if (valid) {
        unsigned pos = (unsigned)(sBlockBase[b] + sWaveBase[w][b] + pre);
        if (pos < (unsigned)BCAP_B)
            buckets[(size_t)b * BCAP_B + pos] = ent;
    }
}

__global__ void __launch_bounds__(256) block_sum_k(const int* __restrict__ deg,
                                                   int* __restrict__ bsum)
{
    int n = blockIdx.x * 256 + threadIdx.x;
    int d = (n < NN) ? deg[n] : 0;
#pragma unroll
    for (int k = 32; k; k >>= 1) d += __shfl_xor(d, k, 64);
    __shared__ int s[4];
    if ((threadIdx.x & 63) == 0) s[threadIdx.x >> 6] = d;
    __syncthreads();
    if (threadIdx.x == 0) bsum[blockIdx.x] = s[0] + s[1] + s[2] + s[3];
}

__global__ void __launch_bounds__(512) scan_bsum_k(const int* __restrict__ bsum,
                                                   int np, int* __restrict__ ebase)
{
    __shared__ int tmp[512];
    int t = threadIdx.x;
    int v = (t < np) ? bsum[t] : 0;
    tmp[t] = v;
    __syncthreads();
    for (int s = 1; s < 512; s <<= 1) {
        int x = tmp[t];
        int add = (t >= s) ? tmp[t - s] : 0;
        __syncthreads();
        tmp[t] = x + add;
        __syncthreads();
    }
    if (t < np) ebase[t] = tmp[t] - v;
}

__global__ void __launch_bounds__(256) scan_write_k(const int* __restrict__ deg,
                                                    const int* __restrict__ ebase,
                                                    int* __restrict__ off,
                                                    int* __restrict__ cursor)
{
    __shared__ int tmp[256];
    int t = threadIdx.x;
    int n = blockIdx.x * 256 + t;
    int d = (n < NN) ? deg[n] : 0;
    tmp[t] = d;
    __syncthreads();
    for (int s = 1; s < 256; s <<= 1) {
        int x = tmp[t];
        int add = (t >= s) ? tmp[t - s] : 0;
        __syncthreads();
        tmp[t] = x + add;
        __syncthreads();
    }
    int excl = tmp[t] - d;
    if (n < NN) {
        int base = ebase[blockIdx.x] + excl;
        off[n] = base;
        cursor[n] = base;
    }
}

// ---------------------------------------------------------------------------
// Pass B: per-slice CSR fill. Group g streams its slice's 1.76 MB bucket and
// scatters into its 800 KB csr slice + 50 KB cursors (fits one XCD L2).
// ---------------------------------------------------------------------------
__global__ void __launch_bounds__(256) fillB_k(const uint2* __restrict__ buckets,
                                               const int* __restrict__ btot,
                                               int* __restrict__ cursor,
                                               unsigned* __restrict__ csr4)
{
    int g = blockIdx.x & (NSLICE - 1);
    int b = blockIdx.x >> 3;
    int cnt = btot[g];
    if (cnt > BCAP_B) cnt = BCAP_B;
    const uint2* bk = buckets + (size_t)g * BCAP_B;
    for (int i = b * 256 + (int)threadIdx.x; i < cnt; i += FB_BPG * 256) {
        uint2 e = bk[i];
        unsigned d = e.y;
        if (d >= (unsigned)NN) continue;
        unsigned pos = (unsigned)atomicAdd(cursor + d, 1);
        if (pos < (unsigned)NE) csr4[pos] = e.x;
    }
}

// ---------------------------------------------------------------------------
// mm1: proj1 = fp16(x@Win_rel), root1 = fp16(x@Win_root + bin).
// ---------------------------------------------------------------------------
__global__ void __launch_bounds__(256) mm1_k(
    const float* __restrict__ x, const float* __restrict__ Wrel,
    const float* __restrict__ Wroot, const float* __restrict__ bin,
    __half* __restrict__ proj1, __half* __restrict__ root1)
{
    __shared__ float sX[128 * 65];
    __shared__ float sW[64 * 68];
    int t = threadIdx.x;
    for (int i = t; i < 64 * 32; i += 256) {
        int k = i >> 5, j = i & 31;
        sW[k * 68 + j] = Wrel[i];
        sW[k * 68 + 32 + j] = Wroot[i];
    }
    int base = blockIdx.x * 128;
    for (int i = t; i < 2048; i += 256) {
        int node = i >> 4;
        int k = (i & 15) * 4;
        int n = base + node;
        if (n >= NN) n = NN - 1;
        float4 v = *(const float4*)(x + (size_t)n * 64 + k);
        float* p = sX + node * 65 + k;
        p[0] = v.x; p[1] = v.y; p[2] = v.z; p[3] = v.w;
    }
    __syncthreads();
    int cg = t & 7;
    int ng = t >> 3;
    int c0 = 8 * cg;
    float acc[4][8] = {};
    for (int k = 0; k < 64; ++k) {
        float xv0 = sX[(4 * ng + 0) * 65 + k];
        float xv1 = sX[(4 * ng + 1) * 65 + k];
        float xv2 = sX[(4 * ng + 2) * 65 + k];
        float xv3 = sX[(4 * ng + 3) * 65 + k];
        float4 w0 = *(const float4*)(sW + k * 68 + c0);
        float4 w1 = *(const float4*)(sW + k * 68 + c0 + 4);
        const float* wp = (const float*)&w0;
#pragma unroll
        for (int j = 0; j < 4; ++j) {
            float w = wp[j];
            acc[0][j] = fmaf(xv0, w, acc[0][j]);
            acc[1][j] = fmaf(xv1, w, acc[1][j]);
            acc[2][j] = fmaf(xv2, w, acc[2][j]);
            acc[3][j] = fmaf(xv3, w, acc[3][j]);
        }
        const float* wq = (const float*)&w1;
#pragma unroll
        for (int j = 0; j < 4; ++j) {
            float w = wq[j];
            acc[0][4 + j] = fmaf(xv0, w, acc[0][4 + j]);
            acc[1][4 + j] = fmaf(xv1, w, acc[1][4 + j]);
            acc[2][4 + j] = fmaf(xv2, w, acc[2][4 + j]);
            acc[3][4 + j] = fmaf(xv3, w, acc[3][4 + j]);
        }
    }
#pragma unroll
    for (int r = 0; r < 4; ++r) {
        int n = base + 4 * ng + r;
        if (n >= NN) break;
        if (cg < 4) {
            *(float4*)(proj1 + (size_t)n * 32 + c0) = pack8(acc[r]);
        } else {
            int c = c0 - 32;
            float v[8];
#pragma unroll
            for (int j = 0; j < 8; ++j) v[j] = acc[r][j] + bin[c + j];
            *(float4*)(root1 + (size_t)n * 32 + c) = pack8(v);
        }
    }
}

// ---------------------------------------------------------------------------
// mm2: proj2 = fp16(h1@Wh_rel), root2 = fp16(h1@Wh_root + bh). K=32.
// ---------------------------------------------------------------------------
__global__ void __launch_bounds__(256) mm2_k(
    const __half* __restrict__ h1, const float* __restrict__ Wrel,
    const float* __restrict__ Wroot, const float* __restrict__ bh,
    __half* __restrict__ proj2, __half* __restrict__ root2)
{
    __shared__ float sX[128 * 33];
    __shared__ float sW[32 * 68];
    int t = threadIdx.x;
    for (int i = t; i < 32 * 32; i += 256) {
        int k = i >> 5, j = i & 31;
        sW[k * 68 + j] = Wrel[i];
        sW[k * 68 + 32 + j] = Wroot[i];
    }
    int base = blockIdx.x * 128;
    for (int i = t; i < 512; i += 256) {
        int node = i >> 2;
        int hs = (i & 3) * 8;
        int n = base + node;
        if (n >= NN) n = NN - 1;
        float4 v = *(const float4*)(h1 + (size_t)n * 32 + hs);
        const __half2* hp = (const __half2*)&v;
        float* p = sX + node * 33 + hs;
#pragma unroll
        for (int u = 0; u < 4; ++u) {
            float2 f2 = __half22float2(hp[u]);
            p[2 * u] = f2.x;
            p[2 * u + 1] = f2.y;
        }
    }
    __syncthreads();
    int cg = t & 7;
    int ng = t >> 3;
    int c0 = 8 * cg;
    float acc[4][8] = {};
    for (int k = 0; k < 32; ++k) {
        float xv0 = sX[(4 * ng + 0) * 33 + k];
        float xv1 = sX[(4 * ng + 1) * 33 + k];
        float xv2 = sX[(4 * ng + 2) * 33 + k];
        float xv3 = sX[(4 * ng + 3) * 33 + k];
        float4 w0 = *(const float4*)(sW + k * 68 + c0);
        float4 w1 = *(const float4*)(sW + k * 68 + c0 + 4);
        const float* wp = (const float*)&w0;
#pragma unroll
        for (int j = 0; j < 4; ++j) {
            float w = wp[j];
            acc[0][j] = fmaf(xv0, w, acc[0][j]);
            acc[1][j] = fmaf(xv1, w, acc[1][j]);
            acc[2][j] = fmaf(xv2, w, acc[2][j]);
            acc[3][j] = fmaf(xv3, w, acc[3][j]);
        }
        const float* wq = (const float*)&w1;
#pragma unroll
        for (int j = 0; j < 4; ++j) {
            float w = wq[j];
            acc[0][4 + j] = fmaf(xv0, w, acc[0][4 + j]);
            acc[1][4 + j] = fmaf(xv1, w, acc[1][4 + j]);
            acc[2][4 + j] = fmaf(xv2, w, acc[2][4 + j]);
            acc[3][4 + j] = fmaf(xv3, w, acc[3][4 + j]);
        }
    }
#pragma unroll
    for (int r = 0; r < 4; ++r) {
        int n = base + 4 * ng + r;
        if (n >= NN) break;
        if (cg < 4) {
            *(float4*)(proj2 + (size_t)n * 32 + c0) = pack8(acc[r]);
        } else {
            int c = c0 - 32;
            float v[8];
#pragma unroll
            for (int j = 0; j < 8; ++j) v[j] = acc[r][j] + bh[c + j];
            *(float4*)(root2 + (size_t)n * 32 + c) = pack8(v);
        }
    }
}

// ---------------------------------------------------------------------------
// agg1 v4: 4 lanes per node (q = feature octet), 16 nodes/wave.
// ---------------------------------------------------------------------------
__global__ void __launch_bounds__(256) agg1_v4(
    const __half* __restrict__ proj1, const __half* __restrict__ root1,
    const unsigned* __restrict__ csr4, const int* __restrict__ off,
    const int* __restrict__ deg, __half* __restrict__ h1)
{
    int t = threadIdx.x;
    int q = t & 3;
    int f0 = q * 8;
    int n = blockIdx.x * 64 + (t >> 2);
    if (n >= NN) return;
    int st = off[n];
    int dg = deg[n];
    if (st < 0) st = 0;
    if (st > NE) st = NE;
    if (dg < 0) dg = 0;
    if (dg > NE - st) dg = NE - st;
    float acc[8] = {0.f, 0.f, 0.f, 0.f, 0.f, 0.f, 0.f, 0.f};
    int i = 0;
    for (; i + 1 < dg; i += 2) {
        unsigned e0 = csr4[st + i];
        unsigned e1 = csr4[st + i + 1];
        float w0 = ent_w(e0), w1 = ent_w(e1);
        float4 r0 = *(const float4*)(proj1 + (size_t)ent_s(e0) * 32 + f0);
        float4 r1 = *(const float4*)(proj1 + (size_t)ent_s(e1) * 32 + f0);
        const __half2* h0 = (const __half2*)&r0;
        const __half2* h1p = (const __half2*)&r1;
#pragma unroll
        for (int u = 0; u < 4; ++u) {
            float2 a = __half22float2(h0[u]);
            float2 b = __half22float2(h1p[u]);
            acc[2 * u] = fmaf(w0, a.x, acc[2 * u]);
            acc[2 * u + 1] = fmaf(w0, a.y, acc[2 * u + 1]);
            acc[2 * u] = fmaf(w1, b.x, acc[2 * u]);
            acc[2 * u + 1] = fmaf(w1, b.y, acc[2 * u + 1]);
        }
    }
    if (i < dg) {
        unsigned e0 = csr4[st + i];
        float w0 = ent_w(e0);
        float4 r0 = *(const float4*)(proj1 + (size_t)ent_s(e0) * 32 + f0);
        const __half2* h0 = (const __half2*)&r0;
#pragma unroll
        for (int u = 0; u < 4; ++u) {
            float2 a = __half22float2(h0[u]);
            acc[2 * u] = fmaf(w0, a.x, acc[2 * u]);
            acc[2 * u + 1] = fmaf(w0, a.y, acc[2 * u + 1]);
        }
    }
    float4 rr = *(const float4*)(root1 + (size_t)n * 32 + f0);
    const __half2* rp = (const __half2*)&rr;
    float h[8];
#pragma unroll
    for (int u = 0; u < 4; ++u) {
        float2 f2 = __half22float2(rp[u]);
        h[2 * u] = fmaxf(acc[2 * u] + f2.x, 0.f);
        h[2 * u + 1] = fmaxf(acc[2 * u + 1] + f2.y, 0.f);
    }
    *(float4*)(h1 + (size_t)n * 32 + f0) = pack8(h);
}

// ---------------------------------------------------------------------------
// agg2 v4: same gather structure; epilogue computes the 4 OUT=1 head dots.
// ---------------------------------------------------------------------------
__global__ void __launch_bounds__(256) agg2_v4(
    const __half* __restrict__ proj2, const __half* __restrict__ root2,
    const float* __restrict__ Wp_rel, const float* __restrict__ Wp_root,
    const float* __restrict__ bp, const float* __restrict__ Wv_rel,
    const float* __restrict__ Wv_root, const float* __restrict__ bv,
    const unsigned* __restrict__ csr4, const int* __restrict__ off,
    const int* __restrict__ deg, float2* __restrict__ pv,
    float* __restrict__ pbase, float* __restrict__ vbase)
{
    __shared__ float sHead[4 * 32];
    if (threadIdx.x < 32) {
        sHead[threadIdx.x] = Wp_rel[threadIdx.x];
        sHead[32 + threadIdx.x] = Wp_root[threadIdx.x];
        sHead[64 + threadIdx.x] = Wv_rel[threadIdx.x];
        sHead[96 + threadIdx.x] = Wv_root[threadIdx.x];
    }
    __syncthreads();
    int t = threadIdx.x;
    int q = t & 3;
    int f0 = q * 8;
    int n = blockIdx.x * 64 + (t >> 2);
    if (n >= NN) return;
    int st = off[n];
    int dg = deg[n];
    if (st < 0) st = 0;
    if (st > NE) st = NE;
    if (dg < 0) dg = 0;
    if (dg > NE - st) dg = NE - st;
    float acc[8] = {0.f, 0.f, 0.f, 0.f, 0.f, 0.f, 0.f, 0.f};
    int i = 0;
    for (; i + 1 < dg; i += 2) {
        unsigned e0 = csr4[st + i];
        unsigned e1 = csr4[st + i + 1];
        float w0 = ent_w(e0), w1 = ent_w(e1);
        float4 r0 = *(const float4*)(proj2 + (size_t)ent_s(e0) * 32 + f0);
        float4 r1 = *(const float4*)(proj2 + (size_t)ent_s(e1) * 32 + f0);
        const __half2* h0 = (const __half2*)&r0;
        const __half2* h1p = (const __half2*)&r1;
#pragma unroll
        for (int u = 0; u < 4; ++u) {
            float2 a = __half22float2(h0[u]);
            float2 b = __half22float2(h1p[u]);
            acc[2 * u] = fmaf(w0, a.x, acc[2 * u]);
            acc[2 * u + 1] = fmaf(w0, a.y, acc[2 * u + 1]);
            acc[2 * u] = fmaf(w1, b.x, acc[2 * u]);
            acc[2 * u + 1] = fmaf(w1, b.y, acc[2 * u + 1]);
        }
    }
    if (i < dg) {
        unsigned e0 = csr4[st + i];
        float w0 = ent_w(e0);
        float4 r0 = *(const float4*)(proj2 + (size_t)ent_s(e0) * 32 + f0);
        const __half2* h0 = (const __half2*)&r0;
#pragma unroll
        for (int u = 0; u < 4; ++u) {
            float2 a = __half22float2(h0[u]);
            acc[2 * u] = fmaf(w0, a.x, acc[2 * u]);
            acc[2 * u + 1] = fmaf(w0, a.y, acc[2 * u + 1]);
        }
    }
    float4 rr = *(const float4*)(root2 + (size_t)n * 32 + f0);
    const __half2* rp = (const __half2*)&rr;
    float h[8];
#pragma unroll
    for (int u = 0; u < 4; ++u) {
        float2 f2 = __half22float2(rp[u]);
        h[2 * u] = fmaxf(acc[2 * u] + f2.x, 0.f);
        h[2 * u + 1] = fmaxf(acc[2 * u + 1] + f2.y, 0.f);
    }
    float prv = 0.f, pov = 0.f, vrv = 0.f, vov = 0.f;
#pragma unroll
    for (int j = 0; j < 8; ++j) {
        prv = fmaf(h[j], sHead[f0 + j], prv);
        pov = fmaf(h[j], sHead[32 + f0 + j], pov);
        vrv = fmaf(h[j], sHead[64 + f0 + j], vrv);
        vov = fmaf(h[j], sHead[96 + f0 + j], vov);
    }
#pragma unroll
    for (int m = 1; m <= 2; m <<= 1) {
        prv += __shfl_xor(prv, m, 64);
        pov += __shfl_xor(pov, m, 64);
        vrv += __shfl_xor(vrv, m, 64);
        vov += __shfl_xor(vov, m, 64);
    }
    if (q == 0) {
        pv[n] = make_float2(prv, vrv);
        pbase[n] = pov + bp[0];
        vbase[n] = vov + bv[0];
    }
}

// ---------------------------------------------------------------------------
// Single-block masked softmax over the ~64 reachable nodes; sparse writes.
// ---------------------------------------------------------------------------
__global__ void __launch_bounds__(256) masked_softmax_k(
    const int* __restrict__ mlist, const int* __restrict__ mcount,
    const unsigned* __restrict__ csr4, const int* __restrict__ off,
    const int* __restrict__ deg, const float2* __restrict__ pv,
    const float* __restrict__ pbase, const float* __restrict__ vbase,
    float* __restrict__ out_p, float* __restrict__ out_v)
{
    __shared__ float sPm[MCAP];
    __shared__ float sV[MCAP];
    __shared__ int sN[MCAP];
    __shared__ float sMx, sSum;
    __shared__ float sred[4];
    int m = mcount[0];
    if (m > MCAP) m = MCAP;
    if (m < 0) m = 0;
    for (int idx = threadIdx.x; idx < m; idx += 256) {
        int n = mlist[idx];
        if ((unsigned)n >= (unsigned)NN) n = 0;
        sN[idx] = n;
        int st = off[n];
        int dg = deg[n];
        if (st < 0) st = 0;
        if (st > NE) st = NE;
        if (dg < 0) dg = 0;
        if (dg > NE - st) dg = NE - st;
        float pa = 0.f, va = 0.f;
        for (int i = 0; i < dg; ++i) {
            unsigned ent = csr4[st + i];
            int s = ent_s(ent);
            float w = ent_w(ent);
            float2 tv = pv[s];
            pa = fmaf(tv.x, w, pa);
            va = fmaf(tv.y, w, va);
        }
        float p = pa + pbase[n];
        sPm[idx] = (p == 0.f) ? -INFINITY : p;
        sV[idx] = va + vbase[n];
    }
    __syncthreads();
    float mx = -INFINITY;
    for (int i = threadIdx.x; i < m; i += 256) mx = fmaxf(mx, sPm[i]);
#pragma unroll
    for (int k = 32; k; k >>= 1) mx = fmaxf(mx, __shfl_xor(mx, k, 64));
    if ((threadIdx.x & 63) == 0) sred[threadIdx.x >> 6] = mx;
    __syncthreads();
    if (threadIdx.x == 0)
        sMx = fmaxf(fmaxf(sred[0], sred[1]), fmaxf(sred[2], sred[3]));
    __syncthreads();
    float sum = 0.f;
    for (int i = threadIdx.x; i < m; i += 256) {
        float x = sPm[i];
        sum += (x == -INFINITY) ? 0.f : expf(x - sMx);
    }
#pragma unroll
    for (int k = 32; k; k >>= 1) sum += __shfl_xor(sum, k, 64);
    if ((threadIdx.x & 63) == 0) sred[threadIdx.x >> 6] = sum;
    __syncthreads();
    if (threadIdx.x == 0) sSum = sred[0] + sred[1] + sred[2] + sred[3];
    __syncthreads();
    for (int idx = threadIdx.x; idx < m; idx += 256) {
        int n = sN[idx];
        float x = sPm[idx];
        out_p[n] = (x == -INFINITY) ? 0.f : expf(x - sMx) / sSum;
        out_v[n] = sV[idx];
    }
}

// ---------------------------------------------------------------------------
extern "C" void kernel_launch(void* const* d_in, const int* in_sizes, int n_in,
                              void* d_out, int out_size, void* d_ws,
                              size_t ws_size, hipStream_t stream)
{
    const float* x        = (const float*)d_in[0];
    const int*   ei       = (const int*)d_in[1];
    const float* ew       = (const float*)d_in[2];
    const int*   cur      = (const int*)d_in[3];
    const float* Win_rel  = (const float*)d_in[4];
    const float* bin_rel  = (const float*)d_in[5];
    const float* Win_root = (const float*)d_in[6];
    const float* Wh_rel   = (const float*)d_in[7];
    const float* bh_rel   = (const float*)d_in[8];
    const float* Wh_root  = (const float*)d_in[9];
    const float* Wp_rel   = (const float*)d_in[10];
    const float* bp       = (const float*)d_in[11];
    const float* Wp_root  = (const float*)d_in[12];
    const float* Wv_rel   = (const float*)d_in[13];
    const float* bv       = (const float*)d_in[14];
    const float* Wv_root  = (const float*)d_in[15];

    const int* srcA = ei;
    const int* dstA = ei + NE;

    // Workspace layout (~44 MB). Buckets (8*220000*8 = 14.1 MB) overlay
    // proj1/root1/h1 (19.2 MB) — buckets dead before mm1 writes proj1.
    char* w8 = (char*)d_ws;
    unsigned* csr4 = (unsigned*)w8;          // 6.4 MB
    int* deg    = (int*)(csr4 + NE);         // NN  } zeroed
    int* maskb  = deg + NN;                  // NN  }  together
    int* mcount = maskb + NN;                // 8   }
    int* off    = mcount + 8;
    int* cursor = off + NN;
    int* bsum   = cursor + NN;               // 512
    int* ebase  = bsum + 512;                // 512
    int* mlist  = ebase + 512;               // MCAP
    int* blkcnt = mlist + MCAP;              // 8*NBK = 50000
    int* blkbase = blkcnt + 8 * NBK;         // 8*NBK
    int* btot   = blkbase + 8 * NBK;         // 8
    __half* proj1 = (__half*)(btot + 8);     // U region start (19.2 MB)
    __half* root1 = proj1 + NW;
    __half* h1    = root1 + NW;
    uint2* buckets = (uint2*)proj1;          // overlays U (14.1 MB < 19.2 MB)
    __half* proj2 = h1 + NW;                 // 6.4 MB
    __half* root2 = proj2 + NW;              // 6.4 MB
    float2* pv    = (float2*)(root2 + NW);   // 800 KB
    float* pbase  = (float*)(pv + NN);       // 400 KB
    float* vbase  = pbase + NN;              // 400 KB

    float* out_p = (float*)d_out;
    float* out_v = out_p + NN;

    const int NB_N   = (NN + 255) / 256;    // 391
    const int NB_MM  = (NN + 127) / 128;    // 782
    const int NB_AGG = (NN + 63) / 64;      // 1563

    hipMemsetAsync(deg, 0, (2 * (size_t)NN + 8) * sizeof(int), stream);
    hipMemsetAsync(d_out, 0, 2 * (size_t)NN * sizeof(float), stream);

    // --- CSR build: deterministic two-pass bucket (no reservation atomics)
    countA_k<<<NBK, 256, 0, stream>>>(srcA, dstA, cur, deg, maskb, mcount,
                                      mlist, blkcnt);
    scan_blk_k<<<8, 256, 0, stream>>>(blkcnt, blkbase, btot);
    writeA_k<<<NBK, 256, 0, stream>>>(srcA, dstA, ew, blkbase, buckets);
    block_sum_k<<<NB_N, 256, 0, stream>>>(deg, bsum);
    scan_bsum_k<<<1, 512, 0, stream>>>(bsum, NB_N, ebase);
    scan_write_k<<<NB_N, 256, 0, stream>>>(deg, ebase, off, cursor);
    fillB_k<<<NSLICE * FB_BPG, 256, 0, stream>>>(buckets, btot, cursor, csr4);

    // --- layer chain ---
    mm1_k<<<NB_MM, 256, 0, stream>>>(x, Win_rel, Win_root, bin_rel, proj1,
                                     root1);
    agg1_v4<<<NB_AGG, 256, 0, stream>>>(proj1, root1, csr4, off, deg, h1);
    mm2_k<<<NB_MM, 256, 0, stream>>>(h1, Wh_rel, Wh_root, bh_rel, proj2, root2);
    agg2_v4<<<NB_AGG, 256, 0, stream>>>(proj2, root2, Wp_rel, Wp_root, bp,
                                        Wv_rel, Wv_root, bv, csr4, off, deg,
                                        pv, pbase, vbase);
    // --- masked softmax (sparse outputs) ---
    masked_softmax_k<<<1, 256, 0, stream>>>(mlist, mcount, csr4, off, deg, pv,
                                            pbase, vbase, out_p, out_v);
}